// Round 2
// baseline (460.035 us; speedup 1.0000x reference)
//
#include <hip/hip_runtime.h>
#include <hip/hip_bf16.h>
#include <math.h>

#define DIMC 768
#define HEADS 12
#define DHD 64
#define NB 16
#define NP 1024
#define MTOT (NB*NP)
#define NQKV (3*DIMC)
#define NBH (NB*HEADS)

typedef __attribute__((ext_vector_type(8))) short bf16x8;
typedef __attribute__((ext_vector_type(4))) float f32x4;

__device__ __forceinline__ short f2bf(float f){
  unsigned u = __builtin_bit_cast(unsigned, f);
  u = (u + 0x7fffu + ((u >> 16) & 1u)) >> 16;
  return (short)u;
}

__device__ __forceinline__ bf16x8 cvt8(float4 a, float4 b){
  bf16x8 v;
  v[0]=f2bf(a.x); v[1]=f2bf(a.y); v[2]=f2bf(a.z); v[3]=f2bf(a.w);
  v[4]=f2bf(b.x); v[5]=f2bf(b.y); v[6]=f2bf(b.z); v[7]=f2bf(b.w);
  return v;
}

// C[M,N] = A[M,K] @ W[N,K]^T + bias, 128x128 tile, BK=32, 4 waves
template<int ABF16, int OUTBF16>
__global__ __launch_bounds__(256) void gemm_bias(
    const void* __restrict__ Ap, const float* __restrict__ Wp,
    const float* __restrict__ bias, void* __restrict__ Cp,
    int N, int K)
{
  __shared__ __align__(16) short As[128][40];
  __shared__ __align__(16) short Bs[128][40];
  const int bm = blockIdx.x * 128, bn = blockIdx.y * 128;
  const int t = threadIdx.x;
  const int lane = t & 63, w = t >> 6;
  const int wr = w >> 1, wc = w & 1;
  const int lr = lane & 15, lg = lane >> 4;
  const int lk = lg * 8;
  const int srow = t >> 1, sh = t & 1;

  f32x4 acc[4][4] = {};

  for (int k0 = 0; k0 < K; k0 += 32) {
    if (ABF16) {
      const short* ar = (const short*)Ap + (size_t)(bm + srow) * K + k0 + sh*16;
      *(bf16x8*)&As[srow][sh*16]   = *(const bf16x8*)ar;
      *(bf16x8*)&As[srow][sh*16+8] = *(const bf16x8*)(ar + 8);
    } else {
      const float* ar = (const float*)Ap + (size_t)(bm + srow) * K + k0 + sh*16;
      float4 f0 = ((const float4*)ar)[0];
      float4 f1 = ((const float4*)ar)[1];
      float4 f2 = ((const float4*)ar)[2];
      float4 f3 = ((const float4*)ar)[3];
      *(bf16x8*)&As[srow][sh*16]   = cvt8(f0, f1);
      *(bf16x8*)&As[srow][sh*16+8] = cvt8(f2, f3);
    }
    {
      const float* wp = Wp + (size_t)(bn + srow) * K + k0 + sh*16;
      float4 f0 = ((const float4*)wp)[0];
      float4 f1 = ((const float4*)wp)[1];
      float4 f2 = ((const float4*)wp)[2];
      float4 f3 = ((const float4*)wp)[3];
      *(bf16x8*)&Bs[srow][sh*16]   = cvt8(f0, f1);
      *(bf16x8*)&Bs[srow][sh*16+8] = cvt8(f2, f3);
    }
    __syncthreads();
    bf16x8 a[4], bv[4];
    #pragma unroll
    for (int i=0;i<4;i++) a[i]  = *(const bf16x8*)&As[wr*64 + i*16 + lr][lk];
    #pragma unroll
    for (int i=0;i<4;i++) bv[i] = *(const bf16x8*)&Bs[wc*64 + i*16 + lr][lk];
    #pragma unroll
    for (int mf=0;mf<4;mf++)
      #pragma unroll
      for (int nf=0;nf<4;nf++)
        acc[mf][nf] = __builtin_amdgcn_mfma_f32_16x16x32_bf16(a[mf], bv[nf], acc[mf][nf], 0,0,0);
    __syncthreads();
  }
  #pragma unroll
  for (int nf=0;nf<4;nf++){
    const int n = bn + wc*64 + nf*16 + lr;
    const float bb = bias[n];
    #pragma unroll
    for (int mf=0;mf<4;mf++)
      #pragma unroll
      for (int i=0;i<4;i++){
        const int m = bm + wr*64 + mf*16 + lg*4 + i;
        const float v = acc[mf][nf][i] + bb;
        if (OUTBF16) ((short*)Cp)[(size_t)m*N + n] = f2bf(v);
        else         ((float*)Cp)[(size_t)m*N + n] = v;
      }
  }
}

// transpose V slice of qkv -> vT[bh][64][1024]
__global__ __launch_bounds__(256) void vtrans(const short* __restrict__ qkv, short* __restrict__ vT)
{
  __shared__ __align__(16) short Ts[64][72];
  const int pt = blockIdx.x, h = blockIdx.y, b = blockIdx.z;
  const int t = threadIdx.x;
  {
    const int r = t >> 2, q = t & 3;
    const short* src = qkv + (size_t)(b*NP + pt*64 + r)*NQKV + 2*DIMC + h*DHD + q*16;
    *(bf16x8*)&Ts[r][q*16]   = *(const bf16x8*)src;
    *(bf16x8*)&Ts[r][q*16+8] = *(const bf16x8*)(src+8);
  }
  __syncthreads();
  {
    const int d = t >> 2, q = t & 3;
    __align__(16) short tmp[16];
    #pragma unroll
    for (int j=0;j<16;j++) tmp[j] = Ts[q*16 + j][d];
    short* dst = vT + ((size_t)((b*HEADS + h)*DHD + d))*NP + pt*64 + q*16;
    *(bf16x8*)dst     = *(bf16x8*)&tmp[0];
    *(bf16x8*)(dst+8) = *(bf16x8*)&tmp[8];
  }
}

// per-column (key) sum of exp(QK^T/8); writes 1/sum
__global__ __launch_bounds__(256) void col_stats(const short* __restrict__ qkv, float* __restrict__ invs)
{
  __shared__ __align__(16) short Ks[128][72];
  __shared__ __align__(16) short Qs[64][72];
  __shared__ float red[4][128];
  const int kc = blockIdx.x, h = blockIdx.y, b = blockIdx.z;
  const int t = threadIdx.x;
  const int lane = t & 63, w = t >> 6;
  const int lr = lane & 15, lg = lane >> 4, lk = lg*8;
  const size_t rowbase = (size_t)(b*NP)*NQKV + h*DHD;
  {
    const int r = t >> 1, half = t & 1;
    const short* src = qkv + rowbase + (size_t)(kc*128 + r)*NQKV + DIMC + half*32;
    #pragma unroll
    for (int c=0;c<4;c++)
      *(bf16x8*)&Ks[r][half*32 + c*8] = *(const bf16x8*)(src + c*8);
  }
  float rsum[8] = {};
  for (int qt=0; qt<16; qt++){
    __syncthreads();
    {
      const int r = t >> 2, q = t & 3;
      const short* src = qkv + rowbase + (size_t)(qt*64 + r)*NQKV + q*16;
      *(bf16x8*)&Qs[r][q*16]   = *(const bf16x8*)src;
      *(bf16x8*)&Qs[r][q*16+8] = *(const bf16x8*)(src+8);
    }
    __syncthreads();
    bf16x8 qa0 = *(const bf16x8*)&Qs[w*16 + lr][lk];
    bf16x8 qa1 = *(const bf16x8*)&Qs[w*16 + lr][32 + lk];
    #pragma unroll
    for (int kf=0; kf<8; kf++){
      f32x4 acc = {};
      bf16x8 kb0 = *(const bf16x8*)&Ks[kf*16 + lr][lk];
      bf16x8 kb1 = *(const bf16x8*)&Ks[kf*16 + lr][32 + lk];
      acc = __builtin_amdgcn_mfma_f32_16x16x32_bf16(qa0, kb0, acc, 0,0,0);
      acc = __builtin_amdgcn_mfma_f32_16x16x32_bf16(qa1, kb1, acc, 0,0,0);
      #pragma unroll
      for (int i=0;i<4;i++) rsum[kf] += __expf(acc[i] * 0.125f);
    }
  }
  #pragma unroll
  for (int kf=0;kf<8;kf++){
    float v = rsum[kf];
    v += __shfl_xor(v, 16);
    v += __shfl_xor(v, 32);
    if (lane < 16) red[w][kf*16 + lr] = v;
  }
  __syncthreads();
  if (t < 128) {
    float s = red[0][t] + red[1][t] + red[2][t] + red[3][t];
    invs[(size_t)(b*HEADS + h)*NP + kc*128 + t] = 1.0f / s;
  }
}

// recompute logits, P = exp(A/8)*inv, MSA += P@V
__global__ __launch_bounds__(256) void attn_pv(const short* __restrict__ qkv, const short* __restrict__ vT,
                                               const float* __restrict__ invs, short* __restrict__ msa)
{
  __shared__ __align__(16) short Qs[64][72];
  __shared__ __align__(16) short Ks[64][72];
  __shared__ __align__(16) short Vs[64][72];
  __shared__ __align__(16) short Ps[4][16][72];
  __shared__ float inv_l[64];
  const int qt = blockIdx.x, h = blockIdx.y, b = blockIdx.z;
  const int t = threadIdx.x;
  const int lane = t & 63, w = t >> 6;
  const int lr = lane & 15, lg = lane >> 4, lk = lg*8;
  const size_t qkvbase = (size_t)(b*NP)*NQKV + h*DHD;
  const size_t bh = (size_t)(b*HEADS + h);
  {
    const int r = t >> 2, q = t & 3;
    const short* src = qkv + qkvbase + (size_t)(qt*64 + r)*NQKV + q*16;
    *(bf16x8*)&Qs[r][q*16]   = *(const bf16x8*)src;
    *(bf16x8*)&Qs[r][q*16+8] = *(const bf16x8*)(src+8);
  }
  __syncthreads();
  bf16x8 qa0 = *(const bf16x8*)&Qs[w*16 + lr][lk];
  bf16x8 qa1 = *(const bf16x8*)&Qs[w*16 + lr][32 + lk];
  f32x4 o[4] = {};
  for (int kt=0; kt<16; kt++){
    __syncthreads();
    {
      const int r = t >> 2, q = t & 3;
      const short* ksrc = qkv + qkvbase + (size_t)(kt*64 + r)*NQKV + DIMC + q*16;
      *(bf16x8*)&Ks[r][q*16]   = *(const bf16x8*)ksrc;
      *(bf16x8*)&Ks[r][q*16+8] = *(const bf16x8*)(ksrc+8);
      const short* vsrc = vT + (bh*DHD + r)*NP + kt*64 + q*16;
      *(bf16x8*)&Vs[r][q*16]   = *(const bf16x8*)vsrc;
      *(bf16x8*)&Vs[r][q*16+8] = *(const bf16x8*)(vsrc+8);
      if (t < 64) inv_l[t] = invs[bh*NP + kt*64 + t];
    }
    __syncthreads();
    f32x4 s[4];
    #pragma unroll
    for (int kf=0;kf<4;kf++){
      f32x4 a = {};
      bf16x8 kb0 = *(const bf16x8*)&Ks[kf*16 + lr][lk];
      bf16x8 kb1 = *(const bf16x8*)&Ks[kf*16 + lr][32 + lk];
      a = __builtin_amdgcn_mfma_f32_16x16x32_bf16(qa0, kb0, a, 0,0,0);
      a = __builtin_amdgcn_mfma_f32_16x16x32_bf16(qa1, kb1, a, 0,0,0);
      s[kf] = a;
    }
    #pragma unroll
    for (int kf=0;kf<4;kf++){
      const float iv = inv_l[kf*16 + lr];
      #pragma unroll
      for (int i=0;i<4;i++){
        const float p = __expf(s[kf][i]*0.125f) * iv;
        Ps[w][lg*4 + i][kf*16 + lr] = f2bf(p);
      }
    }
    __syncthreads();
    bf16x8 pa0 = *(const bf16x8*)&Ps[w][lr][lk];
    bf16x8 pa1 = *(const bf16x8*)&Ps[w][lr][32 + lk];
    #pragma unroll
    for (int df=0;df<4;df++){
      bf16x8 vb0 = *(const bf16x8*)&Vs[df*16 + lr][lk];
      bf16x8 vb1 = *(const bf16x8*)&Vs[df*16 + lr][32 + lk];
      o[df] = __builtin_amdgcn_mfma_f32_16x16x32_bf16(pa0, vb0, o[df], 0,0,0);
      o[df] = __builtin_amdgcn_mfma_f32_16x16x32_bf16(pa1, vb1, o[df], 0,0,0);
    }
  }
  #pragma unroll
  for (int df=0;df<4;df++){
    const int d = h*DHD + df*16 + lr;
    #pragma unroll
    for (int i=0;i<4;i++){
      const int p = qt*64 + w*16 + lg*4 + i;
      msa[((size_t)(b*NP) + p)*DIMC + d] = f2bf(o[df][i]);
    }
  }
}

extern "C" void kernel_launch(void* const* d_in, const int* in_sizes, int n_in,
                              void* d_out, int out_size, void* d_ws, size_t ws_size,
                              hipStream_t stream)
{
  const float* x    = (const float*)d_in[0];
  const float* Wqkv = (const float*)d_in[1];
  const float* bqkv = (const float*)d_in[2];
  const float* Wo   = (const float*)d_in[3];
  const float* bo   = (const float*)d_in[4];
  char* ws = (char*)d_ws;
  short* qkv = (short*)ws;                          // 75,497,472 B  bf16 [16384][2304]
  short* vT  = (short*)(ws + 75497472);             // 25,165,824 B  bf16 [192][64][1024]
  short* msa = (short*)(ws + 100663296);            // 25,165,824 B  bf16 [16384][768]
  float* invs= (float*)(ws + 125829120);            //    786,432 B  f32  [192][1024]

  gemm_bias<0,1><<<dim3(128, 18), 256, 0, stream>>>(x, Wqkv, bqkv, qkv, NQKV, DIMC);
  vtrans<<<dim3(16, HEADS, NB), 256, 0, stream>>>(qkv, vT);
  col_stats<<<dim3(8, HEADS, NB), 256, 0, stream>>>(qkv, invs);
  attn_pv<<<dim3(16, HEADS, NB), 256, 0, stream>>>(qkv, vT, invs, msa);
  gemm_bias<1,0><<<dim3(128, 6), 256, 0, stream>>>(msa, Wo, bo, d_out, DIMC, DIMC);
}

// Round 3
// 416.680 us; speedup vs baseline: 1.1040x; 1.1040x over previous
//
#include <hip/hip_runtime.h>
#include <hip/hip_bf16.h>
#include <math.h>

#define DIMC 768
#define HEADS 12
#define DHD 64
#define NB 16
#define NP 1024
#define NQKV (3*DIMC)

typedef __attribute__((ext_vector_type(8))) short bf16x8;
typedef __attribute__((ext_vector_type(4))) float f32x4;

__device__ __forceinline__ short f2bf(float f){
  unsigned u = __builtin_bit_cast(unsigned, f);
  u = (u + 0x7fffu + ((u >> 16) & 1u)) >> 16;
  return (short)u;
}
__device__ __forceinline__ float bf2f(short s){
  return __builtin_bit_cast(float, ((unsigned)(unsigned short)s) << 16);
}
__device__ __forceinline__ bf16x8 cvt8(float4 a, float4 b){
  bf16x8 v;
  v[0]=f2bf(a.x); v[1]=f2bf(a.y); v[2]=f2bf(a.z); v[3]=f2bf(a.w);
  v[4]=f2bf(b.x); v[5]=f2bf(b.y); v[6]=f2bf(b.z); v[7]=f2bf(b.w);
  return v;
}
__device__ __forceinline__ void glds16(const void* gsrc, void* ldst){
  __builtin_amdgcn_global_load_lds(
      (const __attribute__((address_space(1))) unsigned int*)gsrc,
      (__attribute__((address_space(3))) unsigned int*)ldst, 16, 0, 0);
}

// fp32 -> bf16 bulk convert, 8 elems/thread
__global__ __launch_bounds__(256) void cvt_bf16(const float* __restrict__ in, short* __restrict__ out, int n8)
{
  int i = blockIdx.x*256 + threadIdx.x;
  if (i < n8) {
    float4 f0 = ((const float4*)in)[i*2];
    float4 f1 = ((const float4*)in)[i*2+1];
    ((bf16x8*)out)[i] = cvt8(f0, f1);
  }
}

// C[M,N] = A[M,K] @ B[N,K]^T + bias. A bf16 via global_load_lds.
// BCVT=0: B bf16 via global_load_lds. BCVT=1: B fp32, convert-on-stage.
// blockIdx.x = N-tile (fast), blockIdx.y = M-tile.
template<int BCVT, int OUTBF16>
__global__ __launch_bounds__(256) void gemm_bt(
    const short* __restrict__ A, const void* __restrict__ Bp,
    const float* __restrict__ bias, void* __restrict__ Cp,
    int N, int K)
{
  __shared__ __align__(16) short As[128*32];
  __shared__ __align__(16) short Bs[128*32];
  const int bn = blockIdx.x * 128, bm = blockIdx.y * 128;
  const int t = threadIdx.x;
  const int lane = t & 63, w = t >> 6;
  const int wr = w >> 1, wc = w & 1;
  const int lr = lane & 15, lg = lane >> 4;
  const int srow = lane >> 2;            // 0..15 within 16-row chunk
  const int acol = (lane & 3) * 8;       // short offset within 32-col row

  f32x4 acc[4][4] = {};

  for (int k0 = 0; k0 < K; k0 += 32) {
    // A tile 128x32 bf16: 2 glds issues per wave (16 rows / 1KB each)
    glds16(A + (size_t)(bm + w*32 +  0 + srow)*K + k0 + acol, &As[(w*32 +  0)*32]);
    glds16(A + (size_t)(bm + w*32 + 16 + srow)*K + k0 + acol, &As[(w*32 + 16)*32]);
    if (BCVT) {
      const float* wp = (const float*)Bp + (size_t)(bn + (t>>1))*K + k0 + (t&1)*16;
      float4 f0 = ((const float4*)wp)[0];
      float4 f1 = ((const float4*)wp)[1];
      float4 f2 = ((const float4*)wp)[2];
      float4 f3 = ((const float4*)wp)[3];
      *(bf16x8*)&Bs[(t>>1)*32 + (t&1)*16]     = cvt8(f0, f1);
      *(bf16x8*)&Bs[(t>>1)*32 + (t&1)*16 + 8] = cvt8(f2, f3);
    } else {
      const short* bq = (const short*)Bp;
      glds16(bq + (size_t)(bn + w*32 +  0 + srow)*K + k0 + acol, &Bs[(w*32 +  0)*32]);
      glds16(bq + (size_t)(bn + w*32 + 16 + srow)*K + k0 + acol, &Bs[(w*32 + 16)*32]);
    }
    __syncthreads();
    bf16x8 a[4], b[4];
    #pragma unroll
    for (int i=0;i<4;i++) a[i] = *(const bf16x8*)&As[(wr*64 + i*16 + lr)*32 + lg*8];
    #pragma unroll
    for (int i=0;i<4;i++) b[i] = *(const bf16x8*)&Bs[(wc*64 + i*16 + lr)*32 + lg*8];
    #pragma unroll
    for (int mf=0;mf<4;mf++)
      #pragma unroll
      for (int nf=0;nf<4;nf++)
        acc[mf][nf] = __builtin_amdgcn_mfma_f32_16x16x32_bf16(a[mf], b[nf], acc[mf][nf], 0,0,0);
    __syncthreads();
  }
  #pragma unroll
  for (int nf=0;nf<4;nf++){
    const int n = bn + wc*64 + nf*16 + lr;
    const float bb = bias[n];
    #pragma unroll
    for (int mf=0;mf<4;mf++)
      #pragma unroll
      for (int i=0;i<4;i++){
        const int m = bm + wr*64 + mf*16 + lg*4 + i;
        const float v = acc[mf][nf][i] + bb;
        if (OUTBF16) ((short*)Cp)[(size_t)m*N + n] = f2bf(v);
        else         ((float*)Cp)[(size_t)m*N + n] = v;
      }
  }
}

// transpose V slice of qkv -> vT[bh][64][1024], rows pre-scaled by 1/colsum
__global__ __launch_bounds__(256) void vtrans(const short* __restrict__ qkv,
                                              const float* __restrict__ invs,
                                              short* __restrict__ vT)
{
  __shared__ __align__(16) short Ts[64][72];
  __shared__ float invl[64];
  const int pt = blockIdx.x, h = blockIdx.y, b = blockIdx.z;
  const int t = threadIdx.x;
  const size_t bh = (size_t)(b*HEADS + h);
  if (t < 64) invl[t] = invs[bh*NP + pt*64 + t];
  {
    const int r = t >> 2, q = t & 3;
    const short* src = qkv + (size_t)(b*NP + pt*64 + r)*NQKV + 2*DIMC + h*DHD + q*16;
    *(bf16x8*)&Ts[r][q*16]   = *(const bf16x8*)src;
    *(bf16x8*)&Ts[r][q*16+8] = *(const bf16x8*)(src+8);
  }
  __syncthreads();
  {
    const int d = t >> 2, q = t & 3;
    __align__(16) short tmp[16];
    #pragma unroll
    for (int j=0;j<16;j++) tmp[j] = f2bf(bf2f(Ts[q*16 + j][d]) * invl[q*16 + j]);
    short* dst = vT + (bh*DHD + d)*NP + pt*64 + q*16;
    *(bf16x8*)dst     = *(bf16x8*)&tmp[0];
    *(bf16x8*)(dst+8) = *(bf16x8*)&tmp[8];
  }
}

// per-column (key) sum of exp(QK^T/8); writes 1/sum
__global__ __launch_bounds__(256) void col_stats(const short* __restrict__ qkv, float* __restrict__ invs)
{
  __shared__ __align__(16) short Ks[128][72];
  __shared__ __align__(16) short Qs[64][72];
  __shared__ float red[4][128];
  const int kc = blockIdx.x, h = blockIdx.y, b = blockIdx.z;
  const int t = threadIdx.x;
  const int lane = t & 63, w = t >> 6;
  const int lr = lane & 15, lg = lane >> 4, lk = lg*8;
  const size_t rowbase = (size_t)(b*NP)*NQKV + h*DHD;
  {
    const int r = t >> 1, half = t & 1;
    const short* src = qkv + rowbase + (size_t)(kc*128 + r)*NQKV + DIMC + half*32;
    #pragma unroll
    for (int c=0;c<4;c++)
      *(bf16x8*)&Ks[r][half*32 + c*8] = *(const bf16x8*)(src + c*8);
  }
  float rsum[8] = {};
  for (int qt=0; qt<16; qt++){
    __syncthreads();
    {
      const int r = t >> 2, q = t & 3;
      const short* src = qkv + rowbase + (size_t)(qt*64 + r)*NQKV + q*16;
      *(bf16x8*)&Qs[r][q*16]   = *(const bf16x8*)src;
      *(bf16x8*)&Qs[r][q*16+8] = *(const bf16x8*)(src+8);
    }
    __syncthreads();
    bf16x8 qa0 = *(const bf16x8*)&Qs[w*16 + lr][lk];
    bf16x8 qa1 = *(const bf16x8*)&Qs[w*16 + lr][32 + lk];
    #pragma unroll
    for (int kf=0; kf<8; kf++){
      f32x4 acc = {};
      bf16x8 kb0 = *(const bf16x8*)&Ks[kf*16 + lr][lk];
      bf16x8 kb1 = *(const bf16x8*)&Ks[kf*16 + lr][32 + lk];
      acc = __builtin_amdgcn_mfma_f32_16x16x32_bf16(qa0, kb0, acc, 0,0,0);
      acc = __builtin_amdgcn_mfma_f32_16x16x32_bf16(qa1, kb1, acc, 0,0,0);
      #pragma unroll
      for (int i=0;i<4;i++) rsum[kf] += __expf(acc[i] * 0.125f);
    }
  }
  #pragma unroll
  for (int kf=0;kf<8;kf++){
    float v = rsum[kf];
    v += __shfl_xor(v, 16);
    v += __shfl_xor(v, 32);
    if (lane < 16) red[w][kf*16 + lr] = v;
  }
  __syncthreads();
  if (t < 128) {
    float s = red[0][t] + red[1][t] + red[2][t] + red[3][t];
    invs[(size_t)(b*HEADS + h)*NP + kc*128 + t] = 1.0f / s;
  }
}

// recompute logits, E = exp(A/8), MSA = E @ (V*inv)  (inv folded into vT)
__global__ __launch_bounds__(256) void attn_pv(const short* __restrict__ qkv, const short* __restrict__ vT,
                                               short* __restrict__ msa)
{
  __shared__ __align__(16) short Qs[64][72];
  __shared__ __align__(16) short Ks[64][72];
  __shared__ __align__(16) short Vs[64][72];
  __shared__ __align__(16) short Ps[4][16][72];
  const int qt = blockIdx.x, h = blockIdx.y, b = blockIdx.z;
  const int t = threadIdx.x;
  const int lane = t & 63, w = t >> 6;
  const int lr = lane & 15, lg = lane >> 4, lk = lg*8;
  const size_t qkvbase = (size_t)(b*NP)*NQKV + h*DHD;
  const size_t bh = (size_t)(b*HEADS + h);
  {
    const int r = t >> 2, q = t & 3;
    const short* src = qkv + qkvbase + (size_t)(qt*64 + r)*NQKV + q*16;
    *(bf16x8*)&Qs[r][q*16]   = *(const bf16x8*)src;
    *(bf16x8*)&Qs[r][q*16+8] = *(const bf16x8*)(src+8);
  }
  __syncthreads();
  bf16x8 qa0 = *(const bf16x8*)&Qs[w*16 + lr][lk];
  bf16x8 qa1 = *(const bf16x8*)&Qs[w*16 + lr][32 + lk];
  f32x4 o[4] = {};
  for (int kt=0; kt<16; kt++){
    __syncthreads();
    {
      const int r = t >> 2, q = t & 3;
      const short* ksrc = qkv + qkvbase + (size_t)(kt*64 + r)*NQKV + DIMC + q*16;
      *(bf16x8*)&Ks[r][q*16]   = *(const bf16x8*)ksrc;
      *(bf16x8*)&Ks[r][q*16+8] = *(const bf16x8*)(ksrc+8);
      const short* vsrc = vT + (bh*DHD + r)*NP + kt*64 + q*16;
      *(bf16x8*)&Vs[r][q*16]   = *(const bf16x8*)vsrc;
      *(bf16x8*)&Vs[r][q*16+8] = *(const bf16x8*)(vsrc+8);
    }
    __syncthreads();
    f32x4 s[4];
    #pragma unroll
    for (int kf=0;kf<4;kf++){
      f32x4 a = {};
      bf16x8 kb0 = *(const bf16x8*)&Ks[kf*16 + lr][lk];
      bf16x8 kb1 = *(const bf16x8*)&Ks[kf*16 + lr][32 + lk];
      a = __builtin_amdgcn_mfma_f32_16x16x32_bf16(qa0, kb0, a, 0,0,0);
      a = __builtin_amdgcn_mfma_f32_16x16x32_bf16(qa1, kb1, a, 0,0,0);
      s[kf] = a;
    }
    #pragma unroll
    for (int kf=0;kf<4;kf++){
      #pragma unroll
      for (int i=0;i<4;i++){
        const float p = __expf(s[kf][i]*0.125f);
        Ps[w][lg*4 + i][kf*16 + lr] = f2bf(p);
      }
    }
    __syncthreads();
    bf16x8 pa0 = *(const bf16x8*)&Ps[w][lr][lk];
    bf16x8 pa1 = *(const bf16x8*)&Ps[w][lr][32 + lk];
    #pragma unroll
    for (int df=0;df<4;df++){
      bf16x8 vb0 = *(const bf16x8*)&Vs[df*16 + lr][lk];
      bf16x8 vb1 = *(const bf16x8*)&Vs[df*16 + lr][32 + lk];
      o[df] = __builtin_amdgcn_mfma_f32_16x16x32_bf16(pa0, vb0, o[df], 0,0,0);
      o[df] = __builtin_amdgcn_mfma_f32_16x16x32_bf16(pa1, vb1, o[df], 0,0,0);
    }
  }
  #pragma unroll
  for (int df=0;df<4;df++){
    const int d = h*DHD + df*16 + lr;
    #pragma unroll
    for (int i=0;i<4;i++){
      const int p = qt*64 + w*16 + lg*4 + i;
      msa[((size_t)(b*NP) + p)*DIMC + d] = f2bf(o[df][i]);
    }
  }
}

extern "C" void kernel_launch(void* const* d_in, const int* in_sizes, int n_in,
                              void* d_out, int out_size, void* d_ws, size_t ws_size,
                              hipStream_t stream)
{
  const float* x    = (const float*)d_in[0];
  const float* Wqkv = (const float*)d_in[1];
  const float* bqkv = (const float*)d_in[2];
  const float* Wo   = (const float*)d_in[3];
  const float* bo   = (const float*)d_in[4];
  char* ws = (char*)d_ws;
  // layout (total 126,615,552 B — identical footprint to verified round-2):
  short* qkv   = (short*)ws;                     // 75,497,472  bf16 [16384][2304]
  short* vT    = (short*)(ws + 75497472);        // 25,165,824  bf16 [192][64][1024]
  short* Wqkvb = vT;                             // alias: dead before vtrans writes
  short* msa   = (short*)(ws + 100663296);       // 25,165,824  bf16 [16384][768]
  short* xb    = msa;                            // alias: dead before attn_pv writes
  float* invs  = (float*)(ws + 125829120);       //    786,432  f32  [192][1024]

  cvt_bf16<<<6144, 256, 0, stream>>>(x, xb, (16384*768)/8);
  cvt_bf16<<<864, 256, 0, stream>>>(Wqkv, Wqkvb, (2304*768)/8);
  gemm_bt<0,1><<<dim3(18, 128), 256, 0, stream>>>(xb, Wqkvb, bqkv, qkv, NQKV, DIMC);
  col_stats<<<dim3(8, HEADS, NB), 256, 0, stream>>>(qkv, invs);
  vtrans<<<dim3(16, HEADS, NB), 256, 0, stream>>>(qkv, invs, vT);
  attn_pv<<<dim3(16, HEADS, NB), 256, 0, stream>>>(qkv, vT, msa);
  gemm_bt<1,0><<<dim3(6, 128), 256, 0, stream>>>(msa, Wo, bo, d_out, DIMC, DIMC);
}

// Round 4
// 408.187 us; speedup vs baseline: 1.1270x; 1.0208x over previous
//
#include <hip/hip_runtime.h>
#include <hip/hip_bf16.h>
#include <math.h>

#define DIMC 768
#define HEADS 12
#define DHD 64
#define NB 16
#define NP 1024
#define NQKV (3*DIMC)

typedef __attribute__((ext_vector_type(8))) short bf16x8;
typedef __attribute__((ext_vector_type(4))) float f32x4;

__device__ __forceinline__ short f2bf(float f){
  unsigned u = __builtin_bit_cast(unsigned, f);
  u = (u + 0x7fffu + ((u >> 16) & 1u)) >> 16;
  return (short)u;
}
__device__ __forceinline__ float bf2f(short s){
  return __builtin_bit_cast(float, ((unsigned)(unsigned short)s) << 16);
}
__device__ __forceinline__ bf16x8 cvt8(float4 a, float4 b){
  bf16x8 v;
  v[0]=f2bf(a.x); v[1]=f2bf(a.y); v[2]=f2bf(a.z); v[3]=f2bf(a.w);
  v[4]=f2bf(b.x); v[5]=f2bf(b.y); v[6]=f2bf(b.z); v[7]=f2bf(b.w);
  return v;
}
__device__ __forceinline__ void glds16(const void* gsrc, void* ldst){
  __builtin_amdgcn_global_load_lds(
      (const __attribute__((address_space(1))) unsigned int*)gsrc,
      (__attribute__((address_space(3))) unsigned int*)ldst, 16, 0, 0);
}
// physical block -> logical work id, contiguous chunk per XCD (requires nwg%8==0)
__device__ __forceinline__ int xcd_swz(int p, int nwg){
  return (p & 7) * (nwg >> 3) + (p >> 3);
}

// fp32 -> bf16 bulk convert, 8 elems/thread
__global__ __launch_bounds__(256) void cvt_bf16(const float* __restrict__ in, short* __restrict__ out, int n8)
{
  int i = blockIdx.x*256 + threadIdx.x;
  if (i < n8) {
    float4 f0 = ((const float4*)in)[i*2];
    float4 f1 = ((const float4*)in)[i*2+1];
    ((bf16x8*)out)[i] = cvt8(f0, f1);
  }
}

// C[M,N] = A[M,K] @ B[N,K]^T + bias. A bf16 via global_load_lds.
// BCVT=0: B bf16 via glds. BCVT=1: B fp32, convert-on-stage.
// QSCALE=1: scale columns n<768 by 0.125*log2e (folds attn scale+exp2 into Q).
template<int BCVT, int OUTBF16, int QSCALE>
__global__ __launch_bounds__(256) void gemm_bt(
    const short* __restrict__ A, const void* __restrict__ Bp,
    const float* __restrict__ bias, void* __restrict__ Cp,
    int N, int K, int NX)
{
  __shared__ __align__(16) short As[128*32];
  __shared__ __align__(16) short Bs[128*32];
  const int l = xcd_swz(blockIdx.x, gridDim.x);
  const int bn = (l % NX) * 128, bm = (l / NX) * 128;
  const int t = threadIdx.x;
  const int lane = t & 63, w = t >> 6;
  const int wr = w >> 1, wc = w & 1;
  const int lr = lane & 15, lg = lane >> 4;
  const int srow = lane >> 2;
  const int acol = (lane & 3) * 8;

  f32x4 acc[4][4] = {};

  for (int k0 = 0; k0 < K; k0 += 32) {
    glds16(A + (size_t)(bm + w*32 +  0 + srow)*K + k0 + acol, &As[(w*32 +  0)*32]);
    glds16(A + (size_t)(bm + w*32 + 16 + srow)*K + k0 + acol, &As[(w*32 + 16)*32]);
    if (BCVT) {
      const float* wp = (const float*)Bp + (size_t)(bn + (t>>1))*K + k0 + (t&1)*16;
      float4 f0 = ((const float4*)wp)[0];
      float4 f1 = ((const float4*)wp)[1];
      float4 f2 = ((const float4*)wp)[2];
      float4 f3 = ((const float4*)wp)[3];
      *(bf16x8*)&Bs[(t>>1)*32 + (t&1)*16]     = cvt8(f0, f1);
      *(bf16x8*)&Bs[(t>>1)*32 + (t&1)*16 + 8] = cvt8(f2, f3);
    } else {
      const short* bq = (const short*)Bp;
      glds16(bq + (size_t)(bn + w*32 +  0 + srow)*K + k0 + acol, &Bs[(w*32 +  0)*32]);
      glds16(bq + (size_t)(bn + w*32 + 16 + srow)*K + k0 + acol, &Bs[(w*32 + 16)*32]);
    }
    __syncthreads();
    bf16x8 a[4], b[4];
    #pragma unroll
    for (int i=0;i<4;i++) a[i] = *(const bf16x8*)&As[(wr*64 + i*16 + lr)*32 + lg*8];
    #pragma unroll
    for (int i=0;i<4;i++) b[i] = *(const bf16x8*)&Bs[(wc*64 + i*16 + lr)*32 + lg*8];
    #pragma unroll
    for (int mf=0;mf<4;mf++)
      #pragma unroll
      for (int nf=0;nf<4;nf++)
        acc[mf][nf] = __builtin_amdgcn_mfma_f32_16x16x32_bf16(a[mf], b[nf], acc[mf][nf], 0,0,0);
    __syncthreads();
  }
  #pragma unroll
  for (int nf=0;nf<4;nf++){
    const int n = bn + wc*64 + nf*16 + lr;
    const float bb = bias[n];
    const float sc = (QSCALE && n < DIMC) ? 0.18033688011112042f : 1.0f;
    #pragma unroll
    for (int mf=0;mf<4;mf++)
      #pragma unroll
      for (int i=0;i<4;i++){
        const int m = bm + wr*64 + mf*16 + lg*4 + i;
        const float v = (acc[mf][nf][i] + bb) * sc;
        if (OUTBF16) ((short*)Cp)[(size_t)m*N + n] = f2bf(v);
        else         ((float*)Cp)[(size_t)m*N + n] = v;
      }
  }
}

// transpose V slice of qkv -> vT[bh][64][1024], rows pre-scaled by 1/colsum
__global__ __launch_bounds__(256) void vtrans(const short* __restrict__ qkv,
                                              const float* __restrict__ invs,
                                              short* __restrict__ vT)
{
  __shared__ __align__(16) short Ts[64][72];
  __shared__ float invl[64];
  const int pt = blockIdx.x, h = blockIdx.y, b = blockIdx.z;
  const int t = threadIdx.x;
  const size_t bh = (size_t)(b*HEADS + h);
  if (t < 64) invl[t] = invs[bh*NP + pt*64 + t];
  {
    const int r = t >> 2, q = t & 3;
    const short* src = qkv + (size_t)(b*NP + pt*64 + r)*NQKV + 2*DIMC + h*DHD + q*16;
    *(bf16x8*)&Ts[r][q*16]   = *(const bf16x8*)src;
    *(bf16x8*)&Ts[r][q*16+8] = *(const bf16x8*)(src+8);
  }
  __syncthreads();
  {
    const int d = t >> 2, q = t & 3;
    __align__(16) short tmp[16];
    #pragma unroll
    for (int j=0;j<16;j++) tmp[j] = f2bf(bf2f(Ts[q*16 + j][d]) * invl[q*16 + j]);
    short* dst = vT + (bh*DHD + d)*NP + pt*64 + q*16;
    *(bf16x8*)dst     = *(bf16x8*)&tmp[0];
    *(bf16x8*)(dst+8) = *(bf16x8*)&tmp[8];
  }
}

// per-column (key) sum of exp2(Q'K^T) (scale pre-folded into Q); writes 1/sum
__global__ __launch_bounds__(256) void col_stats(const short* __restrict__ qkv, float* __restrict__ invs)
{
  __shared__ __align__(16) short Ks[128][72];
  __shared__ __align__(16) short Qs[64][72];
  __shared__ float red[4][128];
  const int l = xcd_swz(blockIdx.x, gridDim.x);
  const int kc = l & 7, h = (l >> 3) % HEADS, b = l / (8*HEADS);
  const int t = threadIdx.x;
  const int lane = t & 63, w = t >> 6;
  const int lr = lane & 15, lg = lane >> 4, lk = lg*8;
  const size_t rowbase = (size_t)(b*NP)*NQKV + h*DHD;
  {
    const int r = t >> 1, half = t & 1;
    const short* src = qkv + rowbase + (size_t)(kc*128 + r)*NQKV + DIMC + half*32;
    #pragma unroll
    for (int c=0;c<4;c++)
      *(bf16x8*)&Ks[r][half*32 + c*8] = *(const bf16x8*)(src + c*8);
  }
  float rsum[8] = {};
  for (int qt=0; qt<16; qt++){
    __syncthreads();
    {
      const int r = t >> 2, q = t & 3;
      const short* src = qkv + rowbase + (size_t)(qt*64 + r)*NQKV + q*16;
      *(bf16x8*)&Qs[r][q*16]   = *(const bf16x8*)src;
      *(bf16x8*)&Qs[r][q*16+8] = *(const bf16x8*)(src+8);
    }
    __syncthreads();
    bf16x8 qa0 = *(const bf16x8*)&Qs[w*16 + lr][lk];
    bf16x8 qa1 = *(const bf16x8*)&Qs[w*16 + lr][32 + lk];
    #pragma unroll
    for (int kf=0; kf<8; kf++){
      f32x4 acc = {};
      bf16x8 kb0 = *(const bf16x8*)&Ks[kf*16 + lr][lk];
      bf16x8 kb1 = *(const bf16x8*)&Ks[kf*16 + lr][32 + lk];
      acc = __builtin_amdgcn_mfma_f32_16x16x32_bf16(qa0, kb0, acc, 0,0,0);
      acc = __builtin_amdgcn_mfma_f32_16x16x32_bf16(qa1, kb1, acc, 0,0,0);
      #pragma unroll
      for (int i=0;i<4;i++) rsum[kf] += exp2f(acc[i]);
    }
  }
  #pragma unroll
  for (int kf=0;kf<8;kf++){
    float v = rsum[kf];
    v += __shfl_xor(v, 16);
    v += __shfl_xor(v, 32);
    if (lane < 16) red[w][kf*16 + lr] = v;
  }
  __syncthreads();
  if (t < 128) {
    float s = red[0][t] + red[1][t] + red[2][t] + red[3][t];
    invs[(size_t)(b*HEADS + h)*NP + kc*128 + t] = 1.0f / s;
  }
}

// E = exp2(Q'K^T), MSA = E @ (V*inv). QBLK=128: wave owns 32 q-rows.
__global__ __launch_bounds__(256) void attn_pv(const short* __restrict__ qkv, const short* __restrict__ vT,
                                               short* __restrict__ msa)
{
  __shared__ __align__(16) short Qs[128][72];
  __shared__ __align__(16) short Ks[64][72];
  __shared__ __align__(16) short Vs[64][72];
  __shared__ __align__(16) short Ps[4][16][72];
  const int l = xcd_swz(blockIdx.x, gridDim.x);
  const int qt2 = l & 7, h = (l >> 3) % HEADS, b = l / (8*HEADS);
  const int t = threadIdx.x;
  const int lane = t & 63, w = t >> 6;
  const int lr = lane & 15, lg = lane >> 4, lk = lg*8;
  const size_t qkvbase = (size_t)(b*NP)*NQKV + h*DHD;
  const size_t bh = (size_t)(b*HEADS + h);
  {
    const int r = t >> 1, half = t & 1;
    const short* src = qkv + qkvbase + (size_t)(qt2*128 + r)*NQKV + half*32;
    *(bf16x8*)&Qs[r][half*32]     = *(const bf16x8*)src;
    *(bf16x8*)&Qs[r][half*32 + 8] = *(const bf16x8*)(src+8);
    *(bf16x8*)&Qs[r][half*32 +16] = *(const bf16x8*)(src+16);
    *(bf16x8*)&Qs[r][half*32 +24] = *(const bf16x8*)(src+24);
  }
  __syncthreads();
  bf16x8 qa[2][2];
  #pragma unroll
  for (int g=0; g<2; g++){
    qa[g][0] = *(const bf16x8*)&Qs[w*32 + g*16 + lr][lk];
    qa[g][1] = *(const bf16x8*)&Qs[w*32 + g*16 + lr][32 + lk];
  }
  f32x4 o[2][4] = {};
  for (int kt=0; kt<16; kt++){
    __syncthreads();
    {
      const int r = t >> 2, q = t & 3;
      const short* ksrc = qkv + qkvbase + (size_t)(kt*64 + r)*NQKV + DIMC + q*16;
      *(bf16x8*)&Ks[r][q*16]   = *(const bf16x8*)ksrc;
      *(bf16x8*)&Ks[r][q*16+8] = *(const bf16x8*)(ksrc+8);
      const short* vsrc = vT + (bh*DHD + r)*NP + kt*64 + q*16;
      *(bf16x8*)&Vs[r][q*16]   = *(const bf16x8*)vsrc;
      *(bf16x8*)&Vs[r][q*16+8] = *(const bf16x8*)(vsrc+8);
    }
    __syncthreads();
    #pragma unroll
    for (int g=0; g<2; g++){
      f32x4 s[4];
      #pragma unroll
      for (int kf=0;kf<4;kf++){
        f32x4 a = {};
        bf16x8 kb0 = *(const bf16x8*)&Ks[kf*16 + lr][lk];
        bf16x8 kb1 = *(const bf16x8*)&Ks[kf*16 + lr][32 + lk];
        a = __builtin_amdgcn_mfma_f32_16x16x32_bf16(qa[g][0], kb0, a, 0,0,0);
        a = __builtin_amdgcn_mfma_f32_16x16x32_bf16(qa[g][1], kb1, a, 0,0,0);
        s[kf] = a;
      }
      #pragma unroll
      for (int kf=0;kf<4;kf++)
        #pragma unroll
        for (int i=0;i<4;i++)
          Ps[w][lg*4 + i][kf*16 + lr] = f2bf(exp2f(s[kf][i]));
      // Ps[w] is wave-private: no barrier needed, lgkmcnt ordering suffices
      bf16x8 pa0 = *(const bf16x8*)&Ps[w][lr][lk];
      bf16x8 pa1 = *(const bf16x8*)&Ps[w][lr][32 + lk];
      #pragma unroll
      for (int df=0;df<4;df++){
        bf16x8 vb0 = *(const bf16x8*)&Vs[df*16 + lr][lk];
        bf16x8 vb1 = *(const bf16x8*)&Vs[df*16 + lr][32 + lk];
        o[g][df] = __builtin_amdgcn_mfma_f32_16x16x32_bf16(pa0, vb0, o[g][df], 0,0,0);
        o[g][df] = __builtin_amdgcn_mfma_f32_16x16x32_bf16(pa1, vb1, o[g][df], 0,0,0);
      }
    }
  }
  #pragma unroll
  for (int g=0; g<2; g++)
    #pragma unroll
    for (int df=0;df<4;df++){
      const int d = h*DHD + df*16 + lr;
      #pragma unroll
      for (int i=0;i<4;i++){
        const int p = qt2*128 + w*32 + g*16 + lg*4 + i;
        msa[((size_t)(b*NP) + p)*DIMC + d] = f2bf(o[g][df][i]);
      }
    }
}

extern "C" void kernel_launch(void* const* d_in, const int* in_sizes, int n_in,
                              void* d_out, int out_size, void* d_ws, size_t ws_size,
                              hipStream_t stream)
{
  const float* x    = (const float*)d_in[0];
  const float* Wqkv = (const float*)d_in[1];
  const float* bqkv = (const float*)d_in[2];
  const float* Wo   = (const float*)d_in[3];
  const float* bo   = (const float*)d_in[4];
  char* ws = (char*)d_ws;
  short* qkv   = (short*)ws;                     // 75,497,472  bf16 [16384][2304]
  short* vT    = (short*)(ws + 75497472);        // 25,165,824  bf16 [192][64][1024]
  short* Wqkvb = vT;                             // alias: dead before vtrans writes
  short* msa   = (short*)(ws + 100663296);       // 25,165,824  bf16 [16384][768]
  short* xb    = msa;                            // alias: dead before attn_pv writes
  float* invs  = (float*)(ws + 125829120);       //    786,432  f32  [192][1024]

  cvt_bf16<<<6144, 256, 0, stream>>>(x, xb, (16384*768)/8);
  cvt_bf16<<<864, 256, 0, stream>>>(Wqkv, Wqkvb, (2304*768)/8);
  gemm_bt<0,1,1><<<2304, 256, 0, stream>>>(xb, Wqkvb, bqkv, qkv, NQKV, DIMC, 18);
  col_stats<<<1536, 256, 0, stream>>>(qkv, invs);
  vtrans<<<dim3(16, HEADS, NB), 256, 0, stream>>>(qkv, invs, vT);
  attn_pv<<<1536, 256, 0, stream>>>(qkv, vT, msa);
  gemm_bt<1,0,0><<<768, 256, 0, stream>>>(msa, Wo, bo, d_out, DIMC, DIMC, 6);
}